// Round 2
// baseline (774.668 us; speedup 1.0000x reference)
//
#include <hip/hip_runtime.h>
#include <stdint.h>

#define B_SZ 2
#define S_LEN 2048
#define D_DIM 2048
#define NHEAD 16
#define HD 128
#define HALF 64
#define MROWS (B_SZ * S_LEN)   // 4096

typedef __attribute__((ext_vector_type(8))) __bf16 bf16x8;
typedef __attribute__((ext_vector_type(8))) unsigned short u16x8;
typedef __attribute__((ext_vector_type(4))) float f32x4;

__device__ inline unsigned short f2bf(float x) {
  union { float f; uint32_t u; } c; c.f = x;
  uint32_t r = (c.u + 0x7fffu + ((c.u >> 16) & 1u)) >> 16;
  return (unsigned short)r;
}

__device__ inline void gll16(const void* g, void* l) {
  __builtin_amdgcn_global_load_lds(
      (const __attribute__((address_space(1))) void*)g,
      (__attribute__((address_space(3))) void*)l,
      16, 0, 0);
}

// ---------------- elementwise cast f32 -> bf16 ----------------
__global__ void cast_kernel(const float* __restrict__ in,
                            unsigned short* __restrict__ out, int n4) {
  int i = blockIdx.x * blockDim.x + threadIdx.x;
  int stride = gridDim.x * blockDim.x;
  for (; i < n4; i += stride) {
    float4 v = reinterpret_cast<const float4*>(in)[i];
    ushort4 o;
    o.x = f2bf(v.x); o.y = f2bf(v.y); o.z = f2bf(v.z); o.w = f2bf(v.w);
    reinterpret_cast<ushort4*>(out)[i] = o;
  }
}

// ---------------- GEMM: C[i,j] = sum_k A[i,k]*Bt[j,k] + bias[j] ----------------
// MODE 0: fp32 linear out. MODE 1: bf16 linear out.
// MODE 2: bf16 out written per-head-transposed: Vt[b][h][d][s]
template <int MODE>
__global__ __launch_bounds__(256) void gemm_bt(
    const unsigned short* __restrict__ A, const unsigned short* __restrict__ Bt,
    const float* __restrict__ bias, void* __restrict__ Cv,
    int M, int N, int K) {
  __shared__ __align__(16) unsigned short As[128 * 32];
  __shared__ __align__(16) unsigned short Bs[128 * 32];
  const int tid = threadIdx.x;
  const int lane = tid & 63;
  const int wave = tid >> 6;
  const int bm = blockIdx.y, bn = blockIdx.x;
  const int wr = wave >> 1, wc = wave & 1;
  const int lm = lane & 15, lg = lane >> 4;

  f32x4 acc[4][4] = {};

  for (int k0 = 0; k0 < K; k0 += 32) {
    __syncthreads();
#pragma unroll
    for (int j = 0; j < 2; ++j) {
      int ob = wave * 2048 + j * 1024;
      int o = ob + lane * 16;
      int row = o >> 6;
      int col = (o & 63) >> 1;
      const unsigned short* ga = A + (size_t)(bm * 128 + row) * K + k0 + col;
      gll16(ga, (char*)As + ob);
      const unsigned short* gb = Bt + (size_t)(bn * 128 + row) * K + k0 + col;
      gll16(gb, (char*)Bs + ob);
    }
    __syncthreads();

    bf16x8 af[4], bfr[4];
#pragma unroll
    for (int mi = 0; mi < 4; ++mi)
      af[mi] = *reinterpret_cast<const bf16x8*>(
          &As[(wr * 64 + mi * 16 + lm) * 32 + lg * 8]);
#pragma unroll
    for (int ni = 0; ni < 4; ++ni)
      bfr[ni] = *reinterpret_cast<const bf16x8*>(
          &Bs[(wc * 64 + ni * 16 + lm) * 32 + lg * 8]);
#pragma unroll
    for (int mi = 0; mi < 4; ++mi)
#pragma unroll
      for (int ni = 0; ni < 4; ++ni)
        acc[mi][ni] = __builtin_amdgcn_mfma_f32_16x16x32_bf16(
            af[mi], bfr[ni], acc[mi][ni], 0, 0, 0);
  }

#pragma unroll
  for (int ni = 0; ni < 4; ++ni) {
    int col = bn * 128 + wc * 64 + ni * 16 + lm;
    float bv = bias[col];
    if constexpr (MODE == 2) {
      int h = col >> 7, d = col & (HD - 1);
#pragma unroll
      for (int mi = 0; mi < 4; ++mi) {
        int row0 = bm * 128 + wr * 64 + mi * 16 + lg * 4;
        int b = row0 >> 11, s0 = row0 & (S_LEN - 1);
        ushort4 o;
        o.x = f2bf(acc[mi][ni][0] + bv);
        o.y = f2bf(acc[mi][ni][1] + bv);
        o.z = f2bf(acc[mi][ni][2] + bv);
        o.w = f2bf(acc[mi][ni][3] + bv);
        unsigned short* vt = (unsigned short*)Cv;
        *reinterpret_cast<ushort4*>(
            vt + (((size_t)(b * NHEAD + h) * HD + d) << 11) + s0) = o;
      }
    } else {
#pragma unroll
      for (int mi = 0; mi < 4; ++mi) {
#pragma unroll
        for (int r = 0; r < 4; ++r) {
          int row = bm * 128 + wr * 64 + mi * 16 + lg * 4 + r;
          float v = acc[mi][ni][r] + bv;
          if constexpr (MODE == 1)
            ((unsigned short*)Cv)[(size_t)row * N + col] = f2bf(v);
          else
            ((float*)Cv)[(size_t)row * N + col] = v;
        }
      }
    }
  }
}

// ---------------- RMSNorm (full D) + RoPE, fp32 in -> bf16 out, * outscale ----------------
__global__ __launch_bounds__(256) void norm_rope(
    const float* __restrict__ h, const float* __restrict__ w,
    const float* __restrict__ cosb, const float* __restrict__ sinb,
    unsigned short* __restrict__ out, float outscale) {
  const int row = blockIdx.x;
  const int pos = row & (S_LEN - 1);
  const float* hr = h + (size_t)row * D_DIM;
  const int t = threadIdx.x;
  const int d = t * 8;

  float4 v0 = *reinterpret_cast<const float4*>(hr + d);
  float4 v1 = *reinterpret_cast<const float4*>(hr + d + 4);
  float ss = v0.x * v0.x + v0.y * v0.y + v0.z * v0.z + v0.w * v0.w +
             v1.x * v1.x + v1.y * v1.y + v1.z * v1.z + v1.w * v1.w;
#pragma unroll
  for (int off = 32; off > 0; off >>= 1) ss += __shfl_down(ss, off);
  __shared__ float red[4];
  if ((t & 63) == 0) red[t >> 6] = ss;
  __syncthreads();
  float tot = red[0] + red[1] + red[2] + red[3];
  float inv = rsqrtf(tot * (1.0f / D_DIM) + 1e-6f) * outscale;

  const int p = (d & (HD - 1)) >> 1;
  const float* cp = cosb + pos * HALF + p;
  const float* sp = sinb + pos * HALF + p;
  const float* wp = w + d;

  float c0 = cp[0], c1 = cp[1], c2 = cp[2], c3 = cp[3];
  float s0 = sp[0], s1 = sp[1], s2 = sp[2], s3 = sp[3];
  float a0 = v0.x * inv * wp[0];
  float a1 = v0.y * inv * wp[1];
  float a2 = v0.z * inv * wp[2];
  float a3 = v0.w * inv * wp[3];
  float a4 = v1.x * inv * wp[4];
  float a5 = v1.y * inv * wp[5];
  float a6 = v1.z * inv * wp[6];
  float a7 = v1.w * inv * wp[7];
  u16x8 o;
  o[0] = f2bf(a0 * c0 - a1 * s0);
  o[1] = f2bf(a0 * s0 + a1 * c0);
  o[2] = f2bf(a2 * c1 - a3 * s1);
  o[3] = f2bf(a2 * s1 + a3 * c1);
  o[4] = f2bf(a4 * c2 - a5 * s2);
  o[5] = f2bf(a4 * s2 + a5 * c2);
  o[6] = f2bf(a6 * c3 - a7 * s3);
  o[7] = f2bf(a6 * s3 + a7 * c3);
  *reinterpret_cast<u16x8*>(out + (size_t)row * D_DIM + d) = o;
}

// ---------------- flash attention: 4 waves/block, QBLK=64, KVBLK=64 ----------------
// Q pre-scaled by (1/sqrt(HD))*log2(e) -> softmax in exp2 domain.
// K read row-major from global (L2); V read from pre-transposed Vt[b][h][d][s].
__global__ __launch_bounds__(256) void attn_kernel(
    const unsigned short* __restrict__ Q, const unsigned short* __restrict__ K,
    const unsigned short* __restrict__ Vt, unsigned short* __restrict__ O) {
  // XCD swizzle: 1024 blocks -> each XCD gets 128 consecutive blocks = 4 heads
  const int idx = blockIdx.x;
  const int swz = (idx & 7) * 128 + (idx >> 3);
  const int qb = swz & 31;
  const int h = (swz >> 5) & (NHEAD - 1);
  const int b = swz >> 9;

  const int tid = threadIdx.x;
  const int lane = tid & 63;
  const int wave = tid >> 6;
  const int lm = lane & 15, lg = lane >> 4;

  const size_t base = (size_t)b * S_LEN * D_DIM + (size_t)h * HD;
  const size_t vtb = (size_t)(b * NHEAD + h) * HD * S_LEN;
  const int q0 = qb * 64 + wave * 16;

  __shared__ __align__(16) unsigned short P[4][16][72];

  bf16x8 qf[4];
#pragma unroll
  for (int kc = 0; kc < 4; ++kc)
    qf[kc] = *reinterpret_cast<const bf16x8*>(
        Q + base + (size_t)(q0 + lm) * D_DIM + kc * 32 + lg * 8);

  f32x4 oacc[8] = {};
  float mrow[4], lrow[4];
#pragma unroll
  for (int r = 0; r < 4; ++r) { mrow[r] = -1e30f; lrow[r] = 0.f; }

  for (int kt = 0; kt < S_LEN; kt += 64) {
    f32x4 sc[4] = {};
#pragma unroll
    for (int nt = 0; nt < 4; ++nt) {
#pragma unroll
      for (int kc = 0; kc < 4; ++kc) {
        bf16x8 kf = *reinterpret_cast<const bf16x8*>(
            K + base + (size_t)(kt + nt * 16 + lm) * D_DIM + kc * 32 + lg * 8);
        sc[nt] = __builtin_amdgcn_mfma_f32_16x16x32_bf16(qf[kc], kf, sc[nt], 0, 0, 0);
      }
    }
    float alpha[4];
#pragma unroll
    for (int r = 0; r < 4; ++r) {
      float mx = fmaxf(fmaxf(sc[0][r], sc[1][r]), fmaxf(sc[2][r], sc[3][r]));
#pragma unroll
      for (int off = 8; off >= 1; off >>= 1) mx = fmaxf(mx, __shfl_xor(mx, off));
      float nm = fmaxf(mrow[r], mx);
      alpha[r] = exp2f(mrow[r] - nm);
      mrow[r] = nm;
      float psum = 0.f;
#pragma unroll
      for (int nt = 0; nt < 4; ++nt) {
        float p = exp2f(sc[nt][r] - nm);
        sc[nt][r] = p;
        psum += p;
      }
#pragma unroll
      for (int off = 8; off >= 1; off >>= 1) psum += __shfl_xor(psum, off);
      lrow[r] = lrow[r] * alpha[r] + psum;
    }
#pragma unroll
    for (int dc = 0; dc < 8; ++dc)
#pragma unroll
      for (int r = 0; r < 4; ++r) oacc[dc][r] *= alpha[r];

    // pack P (per-wave tile, no barrier needed)
#pragma unroll
    for (int nt = 0; nt < 4; ++nt)
#pragma unroll
      for (int r = 0; r < 4; ++r)
        P[wave][lg * 4 + r][nt * 16 + lm] = f2bf(sc[nt][r]);

    bf16x8 pa0 = *reinterpret_cast<const bf16x8*>(&P[wave][lm][lg * 8]);
    bf16x8 pa1 = *reinterpret_cast<const bf16x8*>(&P[wave][lm][32 + lg * 8]);

#pragma unroll
    for (int dc = 0; dc < 8; ++dc) {
      const unsigned short* vrow = Vt + vtb + (size_t)(dc * 16 + lm) * S_LEN + kt;
      bf16x8 v0 = *reinterpret_cast<const bf16x8*>(vrow + lg * 8);
      bf16x8 v1 = *reinterpret_cast<const bf16x8*>(vrow + 32 + lg * 8);
      oacc[dc] = __builtin_amdgcn_mfma_f32_16x16x32_bf16(pa0, v0, oacc[dc], 0, 0, 0);
      oacc[dc] = __builtin_amdgcn_mfma_f32_16x16x32_bf16(pa1, v1, oacc[dc], 0, 0, 0);
    }
  }

#pragma unroll
  for (int dc = 0; dc < 8; ++dc) {
#pragma unroll
    for (int r = 0; r < 4; ++r) {
      size_t oi = base + (size_t)(q0 + lg * 4 + r) * D_DIM + dc * 16 + lm;
      O[oi] = f2bf(oacc[dc][r] / lrow[r]);
    }
  }
}

// ---------------- launch ----------------
extern "C" void kernel_launch(void* const* d_in, const int* in_sizes, int n_in,
                              void* d_out, int out_size, void* d_ws, size_t ws_size,
                              hipStream_t stream) {
  const float* x   = (const float*)d_in[0];
  const float* fc  = (const float*)d_in[1];
  const float* fs  = (const float*)d_in[2];
  const float* qw  = (const float*)d_in[3];
  const float* qb  = (const float*)d_in[4];
  const float* kw  = (const float*)d_in[5];
  const float* kb  = (const float*)d_in[6];
  const float* vw  = (const float*)d_in[7];
  const float* vb  = (const float*)d_in[8];
  const float* ow  = (const float*)d_in[9];
  const float* ob  = (const float*)d_in[10];
  const float* qnw = (const float*)d_in[11];
  const float* knw = (const float*)d_in[12];
  float* out = (float*)d_out;

  const size_t MSD = (size_t)MROWS * D_DIM;
  const size_t WSZ = (size_t)D_DIM * D_DIM;
  char* ws = (char*)d_ws;
  unsigned short* xb   = (unsigned short*)ws; ws += MSD * 2;
  unsigned short* qwb  = (unsigned short*)ws; ws += WSZ * 2;
  unsigned short* kwb  = (unsigned short*)ws; ws += WSZ * 2;
  unsigned short* vwb  = (unsigned short*)ws; ws += WSZ * 2;
  unsigned short* owb  = (unsigned short*)ws; ws += WSZ * 2;
  float*          qf   = (float*)ws;          ws += MSD * 4;
  unsigned short* qb16 = (unsigned short*)ws; ws += MSD * 2;
  unsigned short* kb16 = (unsigned short*)ws; ws += MSD * 2;
  unsigned short* vt16 = (unsigned short*)ws; ws += MSD * 2;  // Vt[b][h][d][s]
  unsigned short* ob16 = (unsigned short*)ws; ws += MSD * 2;

  cast_kernel<<<2048, 256, 0, stream>>>(x, xb, (int)(MSD / 4));
  cast_kernel<<<1024, 256, 0, stream>>>(qw, qwb, (int)(WSZ / 4));
  cast_kernel<<<1024, 256, 0, stream>>>(kw, kwb, (int)(WSZ / 4));
  cast_kernel<<<1024, 256, 0, stream>>>(vw, vwb, (int)(WSZ / 4));
  cast_kernel<<<1024, 256, 0, stream>>>(ow, owb, (int)(WSZ / 4));

  dim3 ggrid(D_DIM / 128, MROWS / 128);   // (16, 32)
  gemm_bt<2><<<ggrid, 256, 0, stream>>>(xb, vwb, vb, vt16, MROWS, D_DIM, D_DIM);
  gemm_bt<0><<<ggrid, 256, 0, stream>>>(xb, qwb, qb, qf, MROWS, D_DIM, D_DIM);
  const float qscale = 0.08838834764831845f * 1.4426950408889634f;
  norm_rope<<<MROWS, 256, 0, stream>>>(qf, qnw, fc, fs, qb16, qscale);
  gemm_bt<0><<<ggrid, 256, 0, stream>>>(xb, kwb, kb, qf, MROWS, D_DIM, D_DIM);
  norm_rope<<<MROWS, 256, 0, stream>>>(qf, knw, fc, fs, kb16, 1.0f);

  attn_kernel<<<dim3(S_LEN * NHEAD * B_SZ / 64), 256, 0, stream>>>(qb16, kb16, vt16, ob16);

  gemm_bt<0><<<ggrid, 256, 0, stream>>>(ob16, owb, ob, out, MROWS, D_DIM, D_DIM);
}

// Round 4
// 422.208 us; speedup vs baseline: 1.8348x; 1.8348x over previous
//
#include <hip/hip_runtime.h>
#include <stdint.h>

#define B_SZ 2
#define S_LEN 2048
#define D_DIM 2048
#define NHEAD 16
#define HD 128
#define HALF 64
#define MROWS (B_SZ * S_LEN)   // 4096

typedef __attribute__((ext_vector_type(8))) __bf16 bf16x8;
typedef __attribute__((ext_vector_type(8))) unsigned short u16x8;
typedef __attribute__((ext_vector_type(4))) float f32x4;

__device__ inline unsigned short f2bf(float x) {
  union { float f; uint32_t u; } c; c.f = x;
  uint32_t r = (c.u + 0x7fffu + ((c.u >> 16) & 1u)) >> 16;
  return (unsigned short)r;
}

__device__ inline void gll16(const void* g, void* l) {
  __builtin_amdgcn_global_load_lds(
      (const __attribute__((address_space(1))) void*)g,
      (__attribute__((address_space(3))) void*)l,
      16, 0, 0);
}

// ---------------- elementwise cast f32 -> bf16 ----------------
__global__ void cast_kernel(const float* __restrict__ in,
                            unsigned short* __restrict__ out, int n4) {
  int i = blockIdx.x * blockDim.x + threadIdx.x;
  int stride = gridDim.x * blockDim.x;
  for (; i < n4; i += stride) {
    float4 v = reinterpret_cast<const float4*>(in)[i];
    ushort4 o;
    o.x = f2bf(v.x); o.y = f2bf(v.y); o.z = f2bf(v.z); o.w = f2bf(v.w);
    reinterpret_cast<ushort4*>(out)[i] = o;
  }
}

// ---------------- GEMM: C[i,j] = sum_k A[i,k]*Bt[j,k] + bias[j] ----------------
// MODE 0: fp32 linear out. MODE 1: bf16 linear out.
// MODE 2: bf16 out written per-head-transposed: Vt[b][h][d][s]
template <int MODE>
__global__ __launch_bounds__(256) void gemm_bt(
    const unsigned short* __restrict__ A, const unsigned short* __restrict__ Bt,
    const float* __restrict__ bias, void* __restrict__ Cv,
    int M, int N, int K) {
  __shared__ __align__(16) unsigned short As[128 * 32];
  __shared__ __align__(16) unsigned short Bs[128 * 32];
  const int tid = threadIdx.x;
  const int lane = tid & 63;
  const int wave = tid >> 6;
  const int bm = blockIdx.y, bn = blockIdx.x;
  const int wr = wave >> 1, wc = wave & 1;
  const int lm = lane & 15, lg = lane >> 4;

  f32x4 acc[4][4] = {};

  for (int k0 = 0; k0 < K; k0 += 32) {
    __syncthreads();
#pragma unroll
    for (int j = 0; j < 2; ++j) {
      int ob = wave * 2048 + j * 1024;
      int o = ob + lane * 16;
      int row = o >> 6;
      int col = (o & 63) >> 1;
      const unsigned short* ga = A + (size_t)(bm * 128 + row) * K + k0 + col;
      gll16(ga, (char*)As + ob);
      const unsigned short* gb = Bt + (size_t)(bn * 128 + row) * K + k0 + col;
      gll16(gb, (char*)Bs + ob);
    }
    __syncthreads();

    bf16x8 af[4], bfr[4];
#pragma unroll
    for (int mi = 0; mi < 4; ++mi)
      af[mi] = *reinterpret_cast<const bf16x8*>(
          &As[(wr * 64 + mi * 16 + lm) * 32 + lg * 8]);
#pragma unroll
    for (int ni = 0; ni < 4; ++ni)
      bfr[ni] = *reinterpret_cast<const bf16x8*>(
          &Bs[(wc * 64 + ni * 16 + lm) * 32 + lg * 8]);
#pragma unroll
    for (int mi = 0; mi < 4; ++mi)
#pragma unroll
      for (int ni = 0; ni < 4; ++ni)
        acc[mi][ni] = __builtin_amdgcn_mfma_f32_16x16x32_bf16(
            af[mi], bfr[ni], acc[mi][ni], 0, 0, 0);
  }

#pragma unroll
  for (int ni = 0; ni < 4; ++ni) {
    int col = bn * 128 + wc * 64 + ni * 16 + lm;
    float bv = bias[col];
    if constexpr (MODE == 2) {
      int h = col >> 7, d = col & (HD - 1);
#pragma unroll
      for (int mi = 0; mi < 4; ++mi) {
        int row0 = bm * 128 + wr * 64 + mi * 16 + lg * 4;
        int b = row0 >> 11, s0 = row0 & (S_LEN - 1);
        ushort4 o;
        o.x = f2bf(acc[mi][ni][0] + bv);
        o.y = f2bf(acc[mi][ni][1] + bv);
        o.z = f2bf(acc[mi][ni][2] + bv);
        o.w = f2bf(acc[mi][ni][3] + bv);
        unsigned short* vt = (unsigned short*)Cv;
        *reinterpret_cast<ushort4*>(
            vt + (((size_t)(b * NHEAD + h) * HD + d) << 11) + s0) = o;
      }
    } else {
#pragma unroll
      for (int mi = 0; mi < 4; ++mi) {
#pragma unroll
        for (int r = 0; r < 4; ++r) {
          int row = bm * 128 + wr * 64 + mi * 16 + lg * 4 + r;
          float v = acc[mi][ni][r] + bv;
          if constexpr (MODE == 1)
            ((unsigned short*)Cv)[(size_t)row * N + col] = f2bf(v);
          else
            ((float*)Cv)[(size_t)row * N + col] = v;
        }
      }
    }
  }
}

// ---------------- RMSNorm (full D) + RoPE, fp32 in -> bf16 out, * outscale ----------------
__global__ __launch_bounds__(256) void norm_rope(
    const float* __restrict__ h, const float* __restrict__ w,
    const float* __restrict__ cosb, const float* __restrict__ sinb,
    unsigned short* __restrict__ out, float outscale) {
  const int row = blockIdx.x;
  const int pos = row & (S_LEN - 1);
  const float* hr = h + (size_t)row * D_DIM;
  const int t = threadIdx.x;
  const int d = t * 8;

  float4 v0 = *reinterpret_cast<const float4*>(hr + d);
  float4 v1 = *reinterpret_cast<const float4*>(hr + d + 4);
  float ss = v0.x * v0.x + v0.y * v0.y + v0.z * v0.z + v0.w * v0.w +
             v1.x * v1.x + v1.y * v1.y + v1.z * v1.z + v1.w * v1.w;
#pragma unroll
  for (int off = 32; off > 0; off >>= 1) ss += __shfl_down(ss, off);
  __shared__ float red[4];
  if ((t & 63) == 0) red[t >> 6] = ss;
  __syncthreads();
  float tot = red[0] + red[1] + red[2] + red[3];
  float inv = rsqrtf(tot * (1.0f / D_DIM) + 1e-6f) * outscale;

  const int p = (d & (HD - 1)) >> 1;
  const float* cp = cosb + pos * HALF + p;
  const float* sp = sinb + pos * HALF + p;
  const float* wp = w + d;

  float c0 = cp[0], c1 = cp[1], c2 = cp[2], c3 = cp[3];
  float s0 = sp[0], s1 = sp[1], s2 = sp[2], s3 = sp[3];
  float a0 = v0.x * inv * wp[0];
  float a1 = v0.y * inv * wp[1];
  float a2 = v0.z * inv * wp[2];
  float a3 = v0.w * inv * wp[3];
  float a4 = v1.x * inv * wp[4];
  float a5 = v1.y * inv * wp[5];
  float a6 = v1.z * inv * wp[6];
  float a7 = v1.w * inv * wp[7];
  u16x8 o;
  o[0] = f2bf(a0 * c0 - a1 * s0);
  o[1] = f2bf(a0 * s0 + a1 * c0);
  o[2] = f2bf(a2 * c1 - a3 * s1);
  o[3] = f2bf(a2 * s1 + a3 * c1);
  o[4] = f2bf(a4 * c2 - a5 * s2);
  o[5] = f2bf(a4 * s2 + a5 * c2);
  o[6] = f2bf(a6 * c3 - a7 * s3);
  o[7] = f2bf(a6 * s3 + a7 * c3);
  *reinterpret_cast<u16x8*>(out + (size_t)row * D_DIM + d) = o;
}

// ---------------- flash attention: 4 waves, QBLK=64, KVBLK=64, LDS-staged K/V ----------------
// Q pre-scaled by (1/sqrt(HD))*log2(e) -> softmax in exp2 domain.
// K, Vt staged to LDS via global_load_lds, double-buffered (16KB tile stride!),
// XOR-swizzled (swizzle applied on the GLOBAL source address; LDS dest linear).
// Swapped QK^T: mfma(K,Q) -> P[k][q]; each lane owns one q-row's scores.
__global__ __launch_bounds__(256) void attn_kernel(
    const unsigned short* __restrict__ Q, const unsigned short* __restrict__ K,
    const unsigned short* __restrict__ Vt, unsigned short* __restrict__ O) {
  const int idx = blockIdx.x;
  const int swz = (idx & 7) * 128 + (idx >> 3);
  const int qb = swz & 31;
  const int h = (swz >> 5) & (NHEAD - 1);
  const int b = swz >> 9;

  const int tid = threadIdx.x;
  const int lane = tid & 63;
  const int wave = tid >> 6;
  const int lm = lane & 15, lg = lane >> 4;

  const size_t base = (size_t)b * S_LEN * D_DIM + (size_t)h * HD;
  const size_t vtb = (size_t)(b * NHEAD + h) * HD * S_LEN;
  const int q0 = qb * 64 + wave * 16;

  // LDS: K dbuf 2x16KB (stride 16384B), Vt dbuf 2x16KB, P per-wave
  __shared__ __align__(16) unsigned short Ks[2 * 64 * 128];
  __shared__ __align__(16) unsigned short Vs[2 * 128 * 64];
  __shared__ __align__(16) unsigned short P[4][16][72];

  bf16x8 qf[4];
#pragma unroll
  for (int kc = 0; kc < 4; ++kc)
    qf[kc] = *reinterpret_cast<const bf16x8*>(
        Q + base + (size_t)(q0 + lm) * D_DIM + kc * 32 + lg * 8);

  f32x4 oacc[8] = {};
  float mrow = -1e30f, lrow = 0.f;

  const int pb = wave * 1024 + (lane << 4);   // byte pos in 16KB tile (j adds 4096)

  // stage tile kt into buffer buf (tile = 16384 bytes)
  auto stage = [&](int buf, int kt) {
#pragma unroll
    for (int j = 0; j < 4; ++j) {
      int p = pb + j * 4096;
      // K: rows of 256B (16 chunks), chunk swizzled by row&7
      int kr = p >> 8;
      int kc_ = ((p >> 4) & 15) ^ (kr & 7);
      gll16(K + base + (size_t)(kt + kr) * D_DIM + kc_ * 8,
            (char*)Ks + buf * 16384 + wave * 1024 + j * 4096);
      // Vt: rows of 128B (8 chunks), chunk swizzled by row&7
      int vr = p >> 7;
      int vc_ = ((p >> 4) & 7) ^ (vr & 7);
      gll16(Vt + vtb + (size_t)vr * S_LEN + kt + vc_ * 8,
            (char*)Vs + buf * 16384 + wave * 1024 + j * 4096);
    }
  };

  stage(0, 0);
  __syncthreads();

  const int NT = S_LEN / 64;
  for (int t = 0; t < NT; ++t) {
    const int cur = t & 1;
    if (t + 1 < NT) stage(cur ^ 1, (t + 1) * 64);

    // ---- QK^T (swapped): sc[nt] holds P[k = nt*16 + lg*4 + r][q = lm]
    const char* kbp = (const char*)Ks + cur * 16384;
    f32x4 sc[4] = {};
#pragma unroll
    for (int nt = 0; nt < 4; ++nt) {
      int row = nt * 16 + lm;
#pragma unroll
      for (int kc = 0; kc < 4; ++kc) {
        bf16x8 kf = *reinterpret_cast<const bf16x8*>(
            kbp + row * 256 + (((kc * 4 + lg) ^ (row & 7)) << 4));
        sc[nt] = __builtin_amdgcn_mfma_f32_16x16x32_bf16(kf, qf[kc], sc[nt], 0, 0, 0);
      }
    }

    // ---- online softmax: per-lane q-row (q = lm), 16 scores in regs
    float mx = sc[0][0];
#pragma unroll
    for (int nt = 0; nt < 4; ++nt)
#pragma unroll
      for (int r = 0; r < 4; ++r) mx = fmaxf(mx, sc[nt][r]);
    mx = fmaxf(mx, __shfl_xor(mx, 16));
    mx = fmaxf(mx, __shfl_xor(mx, 32));
    float nm = fmaxf(mrow, mx);
    float alpha = exp2f(mrow - nm);
    float psum = 0.f;
#pragma unroll
    for (int nt = 0; nt < 4; ++nt)
#pragma unroll
      for (int r = 0; r < 4; ++r) {
        float pv = exp2f(sc[nt][r] - nm);
        sc[nt][r] = pv;
        psum += pv;
      }
    psum += __shfl_xor(psum, 16);
    psum += __shfl_xor(psum, 32);
    lrow = lrow * alpha + psum;
    mrow = nm;

    // ---- pack P: row q=lm, cols k — one b64 per nt
#pragma unroll
    for (int nt = 0; nt < 4; ++nt) {
      ushort4 o;
      o.x = f2bf(sc[nt][0]); o.y = f2bf(sc[nt][1]);
      o.z = f2bf(sc[nt][2]); o.w = f2bf(sc[nt][3]);
      *reinterpret_cast<ushort4*>(&P[wave][lm][nt * 16 + lg * 4]) = o;
    }

    // ---- rescale O by alpha (per output row q = lg*4+r)
    float av[4];
#pragma unroll
    for (int r = 0; r < 4; ++r) av[r] = __shfl(alpha, lg * 4 + r);
#pragma unroll
    for (int dc = 0; dc < 8; ++dc)
#pragma unroll
      for (int r = 0; r < 4; ++r) oacc[dc][r] *= av[r];

    // ---- PV
    bf16x8 pa0 = *reinterpret_cast<const bf16x8*>(&P[wave][lm][lg * 8]);
    bf16x8 pa1 = *reinterpret_cast<const bf16x8*>(&P[wave][lm][32 + lg * 8]);
    const char* vbp = (const char*)Vs + cur * 16384;
#pragma unroll
    for (int dc = 0; dc < 8; ++dc) {
      int row = dc * 16 + lm;
      bf16x8 v0 = *reinterpret_cast<const bf16x8*>(
          vbp + row * 128 + ((lg ^ (row & 7)) << 4));
      bf16x8 v1 = *reinterpret_cast<const bf16x8*>(
          vbp + row * 128 + (((4 + lg) ^ (row & 7)) << 4));
      oacc[dc] = __builtin_amdgcn_mfma_f32_16x16x32_bf16(pa0, v0, oacc[dc], 0, 0, 0);
      oacc[dc] = __builtin_amdgcn_mfma_f32_16x16x32_bf16(pa1, v1, oacc[dc], 0, 0, 0);
    }

    __syncthreads();   // drains vmcnt: next buffer staged; all reads of cur done
  }

  float lv[4];
#pragma unroll
  for (int r = 0; r < 4; ++r) lv[r] = 1.0f / __shfl(lrow, lg * 4 + r);
#pragma unroll
  for (int dc = 0; dc < 8; ++dc) {
#pragma unroll
    for (int r = 0; r < 4; ++r) {
      size_t oi = base + (size_t)(q0 + lg * 4 + r) * D_DIM + dc * 16 + lm;
      O[oi] = f2bf(oacc[dc][r] * lv[r]);
    }
  }
}

// ---------------- launch ----------------
extern "C" void kernel_launch(void* const* d_in, const int* in_sizes, int n_in,
                              void* d_out, int out_size, void* d_ws, size_t ws_size,
                              hipStream_t stream) {
  const float* x   = (const float*)d_in[0];
  const float* fc  = (const float*)d_in[1];
  const float* fs  = (const float*)d_in[2];
  const float* qw  = (const float*)d_in[3];
  const float* qb  = (const float*)d_in[4];
  const float* kw  = (const float*)d_in[5];
  const float* kb  = (const float*)d_in[6];
  const float* vw  = (const float*)d_in[7];
  const float* vb  = (const float*)d_in[8];
  const float* ow  = (const float*)d_in[9];
  const float* ob  = (const float*)d_in[10];
  const float* qnw = (const float*)d_in[11];
  const float* knw = (const float*)d_in[12];
  float* out = (float*)d_out;

  const size_t MSD = (size_t)MROWS * D_DIM;
  const size_t WSZ = (size_t)D_DIM * D_DIM;
  char* ws = (char*)d_ws;
  unsigned short* xb   = (unsigned short*)ws; ws += MSD * 2;
  unsigned short* qwb  = (unsigned short*)ws; ws += WSZ * 2;
  unsigned short* kwb  = (unsigned short*)ws; ws += WSZ * 2;
  unsigned short* vwb  = (unsigned short*)ws; ws += WSZ * 2;
  unsigned short* owb  = (unsigned short*)ws; ws += WSZ * 2;
  float*          qf   = (float*)ws;          ws += MSD * 4;
  unsigned short* qb16 = (unsigned short*)ws; ws += MSD * 2;
  unsigned short* kb16 = (unsigned short*)ws; ws += MSD * 2;
  unsigned short* vt16 = (unsigned short*)ws; ws += MSD * 2;  // Vt[b][h][d][s]
  unsigned short* ob16 = (unsigned short*)ws; ws += MSD * 2;

  cast_kernel<<<2048, 256, 0, stream>>>(x, xb, (int)(MSD / 4));
  cast_kernel<<<1024, 256, 0, stream>>>(qw, qwb, (int)(WSZ / 4));
  cast_kernel<<<1024, 256, 0, stream>>>(kw, kwb, (int)(WSZ / 4));
  cast_kernel<<<1024, 256, 0, stream>>>(vw, vwb, (int)(WSZ / 4));
  cast_kernel<<<1024, 256, 0, stream>>>(ow, owb, (int)(WSZ / 4));

  dim3 ggrid(D_DIM / 128, MROWS / 128);   // (16, 32)
  gemm_bt<2><<<ggrid, 256, 0, stream>>>(xb, vwb, vb, vt16, MROWS, D_DIM, D_DIM);
  gemm_bt<0><<<ggrid, 256, 0, stream>>>(xb, qwb, qb, qf, MROWS, D_DIM, D_DIM);
  const float qscale = 0.08838834764831845f * 1.4426950408889634f;
  norm_rope<<<MROWS, 256, 0, stream>>>(qf, qnw, fc, fs, qb16, qscale);
  gemm_bt<0><<<ggrid, 256, 0, stream>>>(xb, kwb, kb, qf, MROWS, D_DIM, D_DIM);
  norm_rope<<<MROWS, 256, 0, stream>>>(qf, knw, fc, fs, kb16, 1.0f);

  attn_kernel<<<dim3(S_LEN * NHEAD * B_SZ / 64), 256, 0, stream>>>(qb16, kb16, vt16, ob16);

  gemm_bt<0><<<ggrid, 256, 0, stream>>>(ob16, owb, ob, out, MROWS, D_DIM, D_DIM);
}